// Round 9
// baseline (724.123 us; speedup 1.0000x reference)
//
#include <hip/hip_runtime.h>
#include <stdint.h>
#include <math.h>

#define TT 1024
#define FF 32
#define HH 64

typedef unsigned int u32;
typedef _Float16 f16;
typedef __attribute__((ext_vector_type(8))) _Float16 half8;  // 8 fp16 = 4 VGPRs (MFMA A/B frag)
typedef __attribute__((ext_vector_type(4))) float v4f;       // MFMA C/D frag

#define L2E  1.44269504088896341f   // log2(e)
#define L2E2 2.88539008177792681f   // 2*log2(e)

// pre-scaled-input nonlinearities (scaling folded into weights/biases)
__device__ __forceinline__ float fsig_s(float s) {           // sigmoid(s/L2E)
    return __builtin_amdgcn_rcpf(1.f + __builtin_amdgcn_exp2f(-s));
}
__device__ __forceinline__ float ftanh_s(float s) {          // tanh(s/L2E2)
    return 2.f * __builtin_amdgcn_rcpf(1.f + __builtin_amdgcn_exp2f(-s)) - 1.f;
}

// load 8 consecutive fp32, scale, -> fp16 octet (RNE)
__device__ __forceinline__ half8 ld8h(const float* p, float sc) {
    float4 a = *(const float4*)p, b = *(const float4*)(p + 4);
    half8 r;
    r[0] = (f16)(a.x * sc); r[1] = (f16)(a.y * sc); r[2] = (f16)(a.z * sc); r[3] = (f16)(a.w * sc);
    r[4] = (f16)(b.x * sc); r[5] = (f16)(b.y * sc); r[6] = (f16)(b.z * sc); r[7] = (f16)(b.w * sc);
    return r;
}

// Round-9 = r8 (712.8 us) + final instruction-count shaves:
//  1. BIAS AS MFMA C-IN: lane (q,n) reg e of D = gate e of unit tile*4+q, so
//     the (gate-scaled) bias is a per-lane constant v4f. Preloaded into bc[6]
//     (even/hi lanes only -- the n<->n^1 pairsum must count bias ONCE) and fed
//     as the C operand of MFMA stage 1. Deletes 4 v_add + one dep stage ahead
//     of every transcendental chain, every step, for zero added per-step work.
//  2. sched_barrier(0) after the barrier removed: the asm "memory" clobber
//     already orders memory ops; the pin was blocking register-only hoisting
//     (next-step bookkeeping) into the barrier shadow.
//  3. Everything else byte-identical to r8 (CST=160 conflict-free layout is
//     load-bearing; setprio/sleep kept).
// Antiphase ledger: two clean mechanisms (initial stagger, sustained setprio
// arbitration) both failed to convert pipe-sum to pipe-max -> treated as
// structural for barrier-stepped 2-blocks/CU. MfmaUtil+VALUBusy = 94%: at
// the SIMD issue floor; MFMA decomposition (72/block-step) proven minimal
// for the per-step mat-vec (B-columns idle by construction).

__global__ __launch_bounds__(256, 2)
void lstm_ae_mfma(const float* __restrict__ x,
                  const float* __restrict__ ewih, const float* __restrict__ ewhh,
                  const float* __restrict__ ebih, const float* __restrict__ ebhh,
                  const float* __restrict__ dwih, const float* __restrict__ dwhh,
                  const float* __restrict__ dbih, const float* __restrict__ dbhh,
                  float* __restrict__ out)
{
    const int b = blockIdx.x;
    const int t = threadIdx.x;
    const int w = t >> 6;        // wave 0..3
    const int wu = __builtin_amdgcn_readfirstlane(w);   // SGPR copy, scalar branches
    const int l = t & 63;
    const int q = l >> 4;        // quad: A/B k-group, D row-group
    const int n = l & 15;        // A row-in-tile / B+D column

    __shared__ __align__(16) f16 Bst[2][2][160];     // [buf][col hi/lo][K(128)+pad]
    __shared__ __align__(16) float xst[2][2048];     // x 64-step chunks, fp32, dbuf

    // ---- persistent A fragments (fp32 -> fp16, gate-scaled) ----
    const float sc = ((n & 3) == 2) ? L2E2 : L2E;
    half8 af[6][3];
#pragma unroll
    for (int i = 0; i < 6; ++i) {
        int tile = w * 6 + i;
        if (tile < 16) {
            int r = (n & 3) * 64 + tile * 4 + (n >> 2);          // enc W row
            af[i][0] = ld8h(ewhh + r * 64 + q * 8, sc);          // k 0..31  (h_enc)
            af[i][1] = ld8h(ewhh + r * 64 + 32 + q * 8, sc);     // k 32..63 (h_enc)
            af[i][2] = ld8h(ewih + r * 32 + q * 8, sc);          // k 64..95 (x)
        } else {
            int r = (n & 3) * 32 + (tile - 16) * 4 + (n >> 2);   // dec V row
            af[i][0] = ld8h(dwih + r * 64 + q * 8, sc);          // k 0..31  (h_enc)
            af[i][1] = ld8h(dwih + r * 64 + 32 + q * 8, sc);     // k 32..63 (h_enc)
            af[i][2] = ld8h(dwhh + r * 32 + q * 8, sc);          // k 96..127 (h_dec)
        }
    }

    // ---- per-tile gate-scaled bias as MFMA C-in (hi/even lanes only) ----
    v4f bc[6];
    {
        const float m = (n & 1) ? 0.f : 1.f;
#pragma unroll
        for (int i = 0; i < 6; ++i) {
            int tile = w * 6 + i;
            float g0, g1, g2, g3;
            if (tile < 16) {
                int uu = tile * 4 + q;
                g0 = (ebih[uu]        + ebhh[uu])        * L2E;
                g1 = (ebih[64 + uu]   + ebhh[64 + uu])   * L2E;
                g2 = (ebih[128 + uu]  + ebhh[128 + uu])  * L2E2;
                g3 = (ebih[192 + uu]  + ebhh[192 + uu])  * L2E;
            } else {
                int uu = (tile - 16) * 4 + q;
                g0 = (dbih[uu]       + dbhh[uu])       * L2E;
                g1 = (dbih[32 + uu]  + dbhh[32 + uu])  * L2E;
                g2 = (dbih[64 + uu]  + dbhh[64 + uu])  * L2E2;
                g3 = (dbih[96 + uu]  + dbhh[96 + uu])  * L2E;
            }
            bc[i][0] = g0 * m; bc[i][1] = g1 * m; bc[i][2] = g2 * m; bc[i][3] = g3 * m;
        }
    }

    // ---- lane-pair roles: pair s=n>>1 (<6) owns tile w*6+s; even=hi, odd=lo ----
    const int sel = n >> 1;                          // 0..7
    const bool act = (n < 12);                       // 6 pairs active
    const int tile_s = w * 6 + (sel < 6 ? sel : 0);  // clamped for inactive lanes
    const bool is_enc = (tile_s < 16);
    const int u = is_enc ? (tile_s * 4 + q) : ((tile_s - 16) * 4 + q);
    float c_st = 0.f;

    // ---- prologue: zero both Bst buffers, stage x chunk 0, x[0] into buf0 ----
    { u32* bz = (u32*)&Bst[0][0][0]; for (int i2 = t; i2 < 2 * 2 * 160 / 2; i2 += 256) bz[i2] = 0u; }
    const float* xb = x + (size_t)b * TT * FF;
    *(float4*)&xst[0][t * 8]     = *(const float4*)(xb + t * 8);
    *(float4*)&xst[0][t * 8 + 4] = *(const float4*)(xb + t * 8 + 4);
    __syncthreads();
    if (t >= 96 && t < 128) Bst[0][0][64 + (t - 96)] = (f16)xst[0][t - 96];
    __syncthreads();

    // ---- antiphase stagger: CU-sharing pair is (b, b+256); delay one of them ----
    if ((b >> 8) & 1) asm volatile("s_sleep 7");

    for (int tt = 0; tt <= TT; ++tt) {
        const int p = tt & 1;

        // x chunk prefetch: issue loads now, write LDS just before the barrier
        float4 px0, px1;
        const int cn = (tt >> 6) + 1;
        const bool pf = ((tt & 63) == 0) && (cn < 16);
        if (pf) {
            px0 = *(const float4*)(xb + cn * 2048 + t * 8);
            px1 = *(const float4*)(xb + cn * 2048 + t * 8 + 4);
        }

        // ---- B fragments (col = n&1 replicated, broadcast reads) ----
        const f16* Bp = &Bst[p][0][0];
        const int cb = (n & 1) * 160 + q * 8;
        half8 bf0 = *(const half8*)(Bp + cb);
        half8 bf1 = *(const half8*)(Bp + cb + 32);
        half8 bf2 = *(const half8*)(Bp + cb + 64);
        half8 bf3 = *(const half8*)(Bp + cb + 96);

        v4f acc[6];
        // MFMA cluster under raised priority (kept from r8)
        __builtin_amdgcn_s_setprio(1);
        // stage 1: bf0 (first LDS return), C-in = gate-scaled bias (hi lanes)
#pragma unroll
        for (int i = 0; i < 6; ++i)
            acc[i] = __builtin_amdgcn_mfma_f32_16x16x32_f16(af[i][0], bf0, bc[i], 0, 0, 0);
        // stage 2: bf1
#pragma unroll
        for (int i = 0; i < 6; ++i)
            acc[i] = __builtin_amdgcn_mfma_f32_16x16x32_f16(af[i][1], bf1, acc[i], 0, 0, 0);
        // stage 3: x (enc tiles) or h_dec (dec tiles) -- SCALAR select via wu
#pragma unroll
        for (int i = 0; i < 6; ++i) {
            half8 bsel;
            if (wu * 6 + i < 16) bsel = bf2; else bsel = bf3;
            acc[i] = __builtin_amdgcn_mfma_f32_16x16x32_f16(af[i][2], bsel, acc[i], 0, 0, 0);
        }
        __builtin_amdgcn_s_setprio(0);

        // ---- select this pair's tile (cndmask chain, static indices) ----
        v4f u_ = acc[0];
#pragma unroll
        for (int i = 1; i < 6; ++i) if (sel == i) u_ = acc[i];

        // ---- hi+lo reduce: lane n <-> n^1 via DPP quad_perm [1,0,3,2] ----
        // bias was added on the even lane only -> counted exactly once here.
        v4f s_;
#pragma unroll
        for (int e = 0; e < 4; ++e) {
            int tmp = __builtin_amdgcn_update_dpp(0, __float_as_int(u_[e]), 0xB1, 0xF, 0xF, true);
            s_[e] = u_[e] + __int_as_float(tmp);
        }

        // ---- unit update (bias already in s_) + h write to buf p^1 ----
        f16* Bw = &Bst[p ^ 1][0][0];
        if (act && (is_enc ? (tt < TT) : (tt >= 1))) {
            float i_ = fsig_s(s_[0]);
            float f_ = fsig_s(s_[1]);
            float g_ = ftanh_s(s_[2]);
            float o_ = fsig_s(s_[3]);
            c_st = f_ * c_st + L2E2 * (i_ * g_);
            float h = o_ * ftanh_s(c_st);
            f16 hi = (f16)h;
            f16 lo = (f16)(h - (float)hi);
            const int kk = is_enc ? u : (96 + u);
            Bw[(n & 1) * 160 + kk] = (n & 1) ? lo : hi;
            if (wu >= 2) {                       // scalar: only waves 2,3 hold dec tiles
                if (!is_enc && !(n & 1))
                    out[(size_t)b * TT * FF + (size_t)(tt - 1) * FF + u] = h;
            }
        } else if (n == 12 || n == 13) {        // stage x for enc step tt+1
            int st = tt + 1;
            if (st < TT) {
                int j = w * 8 + q * 2 + (n - 12);
                Bw[64 + j] = (f16)xst[(st >> 6) & 1][(st & 63) * 32 + j];
            }
        }

        // deferred x-chunk prefetch write (loads in flight across MFMA + update)
        if (pf) {
            *(float4*)&xst[cn & 1][t * 8]     = px0;
            *(float4*)&xst[cn & 1][t * 8 + 4] = px1;
        }

        // ---- raw barrier: drain LDS only; out[] stores stay in flight ----
        asm volatile("s_waitcnt lgkmcnt(0)" ::: "memory");
        __builtin_amdgcn_s_barrier();
    }
}

extern "C" void kernel_launch(void* const* d_in, const int* in_sizes, int n_in,
                              void* d_out, int out_size, void* d_ws, size_t ws_size,
                              hipStream_t stream) {
    (void)in_sizes; (void)n_in; (void)out_size; (void)d_ws; (void)ws_size;
    lstm_ae_mfma<<<512, 256, 0, stream>>>((const float*)d_in[0],
                                          (const float*)d_in[1], (const float*)d_in[2],
                                          (const float*)d_in[3], (const float*)d_in[4],
                                          (const float*)d_in[5], (const float*)d_in[6],
                                          (const float*)d_in[7], (const float*)d_in[8],
                                          (float*)d_out);
}